// Round 1
// baseline (348.753 us; speedup 1.0000x reference)
//
#include <hip/hip_runtime.h>
#include <stdint.h>

// Problem constants (from reference)
#define BATCH   2048
#define IN_BITS 4096
#define N_IN    2048
#define N_ST    1024
#define N_OUT   1024
#define KBITS   14
#define MW      512   // 2^14 bits / 32 = words per packed mem row
#define SROW    96    // s_inp/o_inp packed row words: 3072 bits = 64 (h_in) + 32 (state/s_out)

// float4 counts per mem table
#define IM4 8388608   // N_IN * 16384 / 4
#define SM4 4194304   // N_ST * 16384 / 4
#define OM4 4194304

// ---------------------------------------------------------------------------
// Ballot-layout bit pack. A wave loads 256 consecutive floats (float4/lane),
// forms 4 ballots (one per float4 component), and lanes 0..7 store the 8
// u32 words of the chunk. ZERO cross-lane shuffle (ds_bpermute) ops — the
// old shfl-xor version had a 3-deep DS dependency chain per thread which
// stalled the kernel at ~3.1 TB/s effective.
//
// Layout: chunk c = 256 bits -> words [8c..8c+7]:
//   word 8c + 2j + h  holds bits for floats 256c + 4i + j, i in [32h,32h+32),
//   bit position i&31.
// Consumer remap for bit address a:
//   word = ((a>>5) & ~7) | ((a&3)<<1) | ((a>>7)&1);  shift = (a>>2)&31
__global__ __launch_bounds__(256) void pack_mem_all(const float4* __restrict__ im,
                                                    const float4* __restrict__ sm,
                                                    const float4* __restrict__ om,
                                                    uint32_t* __restrict__ im_p,
                                                    uint32_t* __restrict__ sm_p,
                                                    uint32_t* __restrict__ om_p) {
    int t = blockIdx.x * 256 + threadIdx.x;
    const float4* s;
    uint32_t* d;
    int local;
    if (t < IM4)            { s = im; d = im_p; local = t; }
    else if (t < IM4 + SM4) { s = sm; d = sm_p; local = t - IM4; }
    else                    { s = om; d = om_p; local = t - (IM4 + SM4); }
    float4 v = s[local];
    unsigned long long b0 = __ballot(v.x == 1.0f);
    unsigned long long b1 = __ballot(v.y == 1.0f);
    unsigned long long b2 = __ballot(v.z == 1.0f);
    unsigned long long b3 = __ballot(v.w == 1.0f);
    int lane = threadIdx.x & 63;
    if (lane < 8) {
        unsigned long long bj = (lane & 4) ? ((lane & 2) ? b3 : b2)
                                           : ((lane & 2) ? b1 : b0);
        uint32_t w = (lane & 1) ? (uint32_t)(bj >> 32) : (uint32_t)bj;
        d[((local >> 6) << 3) + lane] = w;   // 8 lanes -> 32B contiguous
    }
}

// Ballot-layout pack of input_bits (rows = 4096 bits = 16 chunks, 128 words).
__global__ __launch_bounds__(256) void pack_input(const int4* __restrict__ src,
                                                  uint32_t* __restrict__ dst) {
    int t = blockIdx.x * 256 + threadIdx.x;  // one int4 (4 bits) per thread
    int4 v = src[t];
    unsigned long long b0 = __ballot(v.x == 1);
    unsigned long long b1 = __ballot(v.y == 1);
    unsigned long long b2 = __ballot(v.z == 1);
    unsigned long long b3 = __ballot(v.w == 1);
    int lane = threadIdx.x & 63;
    if (lane < 8) {
        unsigned long long bj = (lane & 4) ? ((lane & 2) ? b3 : b2)
                                           : ((lane & 2) ? b1 : b0);
        uint32_t w = (lane & 1) ? (uint32_t)(bj >> 32) : (uint32_t)bj;
        dst[((t >> 6) << 3) + lane] = w;
    }
}

// Coalesced pack of state_bits into buf_s at word offset 64, row stride SROW.
// Stays LINEAR layout (matches the ram_layer ballot writes for words 0..63),
// so the SROW=96 consumers keep the simple wd/sh mapping.
__global__ __launch_bounds__(256) void pack_state(const int4* __restrict__ src,
                                                  uint32_t* __restrict__ dst) {
    int t = blockIdx.x * 256 + threadIdx.x;  // one int4 per thread; row = 1024 bits
    int4 v = src[t];
    uint32_t nib = (uint32_t)(v.x == 1) | ((uint32_t)(v.y == 1) << 1) |
                   ((uint32_t)(v.z == 1) << 2) | ((uint32_t)(v.w == 1) << 3);
    int lane = threadIdx.x & 63;
    uint32_t w = nib << (4 * (lane & 7));
    w |= __shfl_xor(w, 1, 64);
    w |= __shfl_xor(w, 2, 64);
    w |= __shfl_xor(w, 4, 64);
    if ((lane & 7) == 0) {
        int g = t >> 3;          // global word index
        int r = g >> 5;          // 32 words per row
        int c = g & 31;
        dst[(long)r * SROW + 64 + c] = w;
    }
}

// ---------------------------------------------------------------------------
// RAM layer: lane = neuron (64 consecutive per wave), block stages BCHUNK
// packed batch rows in LDS. Per (b,n): gather 14 bits from LDS -> 14-bit
// address (k=0 is MSB per reference weights) -> 1 gather into packed mem row
// (ballot layout -> remapped word/shift).
// MODE 0: write ballot bits to dst0 and dst1 at word offset 0 (stride SROW)
// MODE 1: write ballot bits to dst0 at word offset 64 (stride SROW)
// MODE 2: write floats to fout [b*N_OUT + n]
template <int SRCW, int BCHUNK, int MODE>
__global__ __launch_bounds__(256) void ram_layer(const uint32_t* __restrict__ src,
                                                 const int* __restrict__ conn,
                                                 const uint32_t* __restrict__ memp,
                                                 uint32_t* __restrict__ dst0,
                                                 uint32_t* __restrict__ dst1,
                                                 float* __restrict__ fout) {
    __shared__ uint32_t lds[BCHUNK * SRCW];
    const int tid = threadIdx.x;
    const int b0 = blockIdx.y * BCHUNK;

    // Stage BCHUNK contiguous packed rows (row stride == SRCW words, no pad).
    {
        const uint4* g = (const uint4*)(src + (long)b0 * SRCW);
        uint4* l = (uint4*)lds;
        constexpr int NV = BCHUNK * SRCW / 4;
        for (int i = tid; i < NV; i += 256) l[i] = g[i];
    }
    __syncthreads();

    const int n = blockIdx.x * 256 + tid;
    int wd[KBITS], sh[KBITS];
#pragma unroll
    for (int k = 0; k < KBITS; k++) {
        int idx = conn[n * KBITS + k];
        if (SRCW == 128) {
            // bits1 is ballot layout
            wd[k] = ((idx >> 5) & ~7) | ((idx & 3) << 1) | ((idx >> 7) & 1);
            sh[k] = (idx >> 2) & 31;
        } else {
            // SROW=96 sources are linear layout
            wd[k] = idx >> 5;
            sh[k] = idx & 31;
        }
    }
    const uint32_t* mrow = memp + (long)n * MW;
    const int lane = tid & 63;
    const int nbase = blockIdx.x * 256 + (tid & ~63);  // wave's neuron base

#pragma unroll 4
    for (int bb = 0; bb < BCHUNK; ++bb) {
        const uint32_t* row = lds + bb * SRCW;
        uint32_t addr = 0;
#pragma unroll
        for (int k = 0; k < KBITS; k++)
            addr = (addr << 1) | ((row[wd[k]] >> sh[k]) & 1u);
        // mem tables are ballot layout: remap bit address -> (word, shift)
        uint32_t mw = ((addr >> 5) & ~7u) | ((addr & 3u) << 1) | ((addr >> 7) & 1u);
        uint32_t bit = (mrow[mw] >> ((addr >> 2) & 31u)) & 1u;
        const int b = b0 + bb;
        if (MODE == 2) {
            fout[(long)b * N_OUT + n] = (float)bit;
        } else {
            unsigned long long m = __ballot(bit != 0);
            if (lane == 0) {
                if (MODE == 0) {
                    *(unsigned long long*)(dst0 + (long)b * SROW + (nbase >> 5)) = m;
                    *(unsigned long long*)(dst1 + (long)b * SROW + (nbase >> 5)) = m;
                } else {
                    *(unsigned long long*)(dst0 + (long)b * SROW + 64 + (nbase >> 5)) = m;
                }
            }
        }
    }
}

// ---------------------------------------------------------------------------
extern "C" void kernel_launch(void* const* d_in, const int* in_sizes, int n_in,
                              void* d_out, int out_size, void* d_ws, size_t ws_size,
                              hipStream_t stream) {
    const int*   input_bits = (const int*)d_in[0];
    const int*   state_bits = (const int*)d_in[1];
    const int*   in_conn    = (const int*)d_in[2];
    const float* in_mem     = (const float*)d_in[3];
    const int*   st_conn    = (const int*)d_in[4];
    const float* st_mem     = (const float*)d_in[5];
    const int*   out_conn   = (const int*)d_in[6];
    const float* out_mem    = (const float*)d_in[7];
    float*       out        = (float*)d_out;

    // Workspace layout (all 256B-aligned):
    //   bits1 : [B][128] u32  = 1 MB   (packed input_bits, ballot layout)
    //   buf_s : [B][96]  u32  = 768 KB (s_inp bits: h_in | state, linear)
    //   buf_o : [B][96]  u32  = 768 KB (o_inp bits: h_in | s_out, linear)
    //   im_p  : [2048][512]   = 4 MB   (ballot layout)
    //   sm_p  : [1024][512]   = 2 MB   (ballot layout)
    //   om_p  : [1024][512]   = 2 MB   (ballot layout)
    char* ws = (char*)d_ws;
    uint32_t* bits1 = (uint32_t*)(ws);
    uint32_t* buf_s = (uint32_t*)(ws + 1048576);
    uint32_t* buf_o = (uint32_t*)(ws + 1048576 + 786432);
    uint32_t* im_p  = (uint32_t*)(ws + 1048576 + 2 * 786432);
    uint32_t* sm_p  = (uint32_t*)(ws + 1048576 + 2 * 786432 + 4194304);
    uint32_t* om_p  = (uint32_t*)(ws + 1048576 + 2 * 786432 + 4194304 + 2097152);

    // Bit-pack inputs (ballot layout; no cross-lane shuffles).
    pack_input<<<(BATCH * IN_BITS / 4) / 256, 256, 0, stream>>>((const int4*)input_bits, bits1);
    pack_state<<<(BATCH * N_ST / 4) / 256, 256, 0, stream>>>((const int4*)state_bits, buf_s);
    pack_mem_all<<<(IM4 + SM4 + OM4) / 256, 256, 0, stream>>>(
        (const float4*)in_mem, (const float4*)st_mem, (const float4*)out_mem,
        im_p, sm_p, om_p);

    // Layer 1: input_bits -> h_in (written into both buf_s and buf_o, words 0..63)
    ram_layer<128, 16, 0><<<dim3(N_IN / 256, BATCH / 16), 256, 0, stream>>>(
        bits1, in_conn, im_p, buf_s, buf_o, nullptr);
    // Layer 2: s_inp -> s_out (into buf_o words 64..95)
    ram_layer<SROW, 8, 1><<<dim3(N_ST / 256, BATCH / 8), 256, 0, stream>>>(
        buf_s, st_conn, sm_p, buf_o, nullptr, nullptr);
    // Layer 3: o_inp -> output floats
    ram_layer<SROW, 8, 2><<<dim3(N_OUT / 256, BATCH / 8), 256, 0, stream>>>(
        buf_o, out_conn, om_p, nullptr, nullptr, out);
}

// Round 2
// 336.472 us; speedup vs baseline: 1.0365x; 1.0365x over previous
//
#include <hip/hip_runtime.h>
#include <stdint.h>

// Problem constants (from reference)
#define BATCH   2048
#define IN_BITS 4096
#define N_IN    2048
#define N_ST    1024
#define N_OUT   1024
#define KBITS   14
#define MW      512   // 2^14 bits / 32 = words per packed mem row
#define SROW    96    // s_inp/o_inp packed row words: 3072 bits = 64 (h_in) + 32 (state/s_out)

// float4 counts per mem table
#define IM4 8388608   // N_IN * 16384 / 4
#define SM4 4194304   // N_ST * 16384 / 4
#define OM4 4194304
#define GS  524288    // grid-stride: 2048 blocks * 256 threads

typedef float f32x4 __attribute__((ext_vector_type(4)));
typedef int   i32x4 __attribute__((ext_vector_type(4)));

// ---------------------------------------------------------------------------
// Ballot-layout bit pack, grid-strided.
// R1 finding: the one-load-per-thread version ran at a flat 84 us even with
// 100% L3 hits (FETCH~0 replay) -> concurrency-limited, not BW-limited.
// Now: 2048 blocks, each thread walks 32 chunks (stride GS float4s). The
// 32-way unroll has COMPILE-TIME table selection (table boundaries are
// multiples of GS) and gives the compiler 32 independent 16B loads per lane
// to batch -> deep MLP. Loads are non-temporal: this 256 MB stream is
// consumed once and must not evict the packed tables the ram_layers gather.
//
// Layout per 256-bit chunk c -> words [8c..8c+7]:
//   word 8c + 2j + h holds bits of floats 256c + 4i + j, i in [32h,32h+32),
//   bit position i&31.
// Consumer remap for bit address a:
//   word = ((a>>5) & ~7) | ((a&3)<<1) | ((a>>7)&1);  shift = (a>>2)&31
__global__ __launch_bounds__(256) void pack_mem_all(const float* __restrict__ im,
                                                    const float* __restrict__ sm,
                                                    const float* __restrict__ om,
                                                    uint32_t* __restrict__ im_p,
                                                    uint32_t* __restrict__ sm_p,
                                                    uint32_t* __restrict__ om_p) {
    const int t = blockIdx.x * 256 + threadIdx.x;   // [0, GS)
    const int lane = threadIdx.x & 63;
#pragma unroll
    for (int c = 0; c < 32; ++c) {
        const float* s; uint32_t* d; int cl;
        if (c < 16)      { s = im; d = im_p; cl = c; }
        else if (c < 24) { s = sm; d = sm_p; cl = c - 16; }
        else             { s = om; d = om_p; cl = c - 24; }
        const long i = (long)cl * GS + t;            // float4 index within table
        f32x4 v = __builtin_nontemporal_load((const f32x4*)s + i);
        unsigned long long b0 = __ballot(v[0] == 1.0f);
        unsigned long long b1 = __ballot(v[1] == 1.0f);
        unsigned long long b2 = __ballot(v[2] == 1.0f);
        unsigned long long b3 = __ballot(v[3] == 1.0f);
        if (lane < 8) {
            unsigned long long bj = (lane & 4) ? ((lane & 2) ? b3 : b2)
                                               : ((lane & 2) ? b1 : b0);
            uint32_t w = (lane & 1) ? (uint32_t)(bj >> 32) : (uint32_t)bj;
            d[((i >> 6) << 3) + lane] = w;   // 8 lanes -> 32B contiguous
        }
    }
}

// Ballot-layout pack of input_bits (rows = 4096 bits = 16 chunks, 128 words).
// Grid-strided the same way: 2048 blocks, 4 int4s per thread.
__global__ __launch_bounds__(256) void pack_input(const int* __restrict__ src,
                                                  uint32_t* __restrict__ dst) {
    const int t = blockIdx.x * 256 + threadIdx.x;   // [0, GS)
    const int lane = threadIdx.x & 63;
#pragma unroll
    for (int c = 0; c < 4; ++c) {
        const long i = (long)c * GS + t;            // int4 index
        i32x4 v = __builtin_nontemporal_load((const i32x4*)src + i);
        unsigned long long b0 = __ballot(v[0] == 1);
        unsigned long long b1 = __ballot(v[1] == 1);
        unsigned long long b2 = __ballot(v[2] == 1);
        unsigned long long b3 = __ballot(v[3] == 1);
        if (lane < 8) {
            unsigned long long bj = (lane & 4) ? ((lane & 2) ? b3 : b2)
                                               : ((lane & 2) ? b1 : b0);
            uint32_t w = (lane & 1) ? (uint32_t)(bj >> 32) : (uint32_t)bj;
            dst[((i >> 6) << 3) + lane] = w;
        }
    }
}

// Coalesced pack of state_bits into buf_s at word offset 64, row stride SROW.
// Stays LINEAR layout (matches the ram_layer ballot writes for words 0..63),
// so the SROW=96 consumers keep the simple wd/sh mapping. Tiny (8 MB read),
// left untouched.
__global__ __launch_bounds__(256) void pack_state(const int4* __restrict__ src,
                                                  uint32_t* __restrict__ dst) {
    int t = blockIdx.x * 256 + threadIdx.x;  // one int4 per thread; row = 1024 bits
    int4 v = src[t];
    uint32_t nib = (uint32_t)(v.x == 1) | ((uint32_t)(v.y == 1) << 1) |
                   ((uint32_t)(v.z == 1) << 2) | ((uint32_t)(v.w == 1) << 3);
    int lane = threadIdx.x & 63;
    uint32_t w = nib << (4 * (lane & 7));
    w |= __shfl_xor(w, 1, 64);
    w |= __shfl_xor(w, 2, 64);
    w |= __shfl_xor(w, 4, 64);
    if ((lane & 7) == 0) {
        int g = t >> 3;          // global word index
        int r = g >> 5;          // 32 words per row
        int c = g & 31;
        dst[(long)r * SROW + 64 + c] = w;
    }
}

// ---------------------------------------------------------------------------
// RAM layer: lane = neuron (64 consecutive per wave), block stages BCHUNK
// packed batch rows in LDS. Per (b,n): gather 14 bits from LDS -> 14-bit
// address (k=0 is MSB per reference weights) -> 1 gather into packed mem row
// (ballot layout -> remapped word/shift).
// MODE 0: write ballot bits to dst0 and dst1 at word offset 0 (stride SROW)
// MODE 1: write ballot bits to dst0 at word offset 64 (stride SROW)
// MODE 2: write floats to fout [b*N_OUT + n]
template <int SRCW, int BCHUNK, int MODE>
__global__ __launch_bounds__(256) void ram_layer(const uint32_t* __restrict__ src,
                                                 const int* __restrict__ conn,
                                                 const uint32_t* __restrict__ memp,
                                                 uint32_t* __restrict__ dst0,
                                                 uint32_t* __restrict__ dst1,
                                                 float* __restrict__ fout) {
    __shared__ uint32_t lds[BCHUNK * SRCW];
    const int tid = threadIdx.x;
    const int b0 = blockIdx.y * BCHUNK;

    // Stage BCHUNK contiguous packed rows (row stride == SRCW words, no pad).
    {
        const uint4* g = (const uint4*)(src + (long)b0 * SRCW);
        uint4* l = (uint4*)lds;
        constexpr int NV = BCHUNK * SRCW / 4;
        for (int i = tid; i < NV; i += 256) l[i] = g[i];
    }
    __syncthreads();

    const int n = blockIdx.x * 256 + tid;
    int wd[KBITS], sh[KBITS];
#pragma unroll
    for (int k = 0; k < KBITS; k++) {
        int idx = conn[n * KBITS + k];
        if (SRCW == 128) {
            // bits1 is ballot layout
            wd[k] = ((idx >> 5) & ~7) | ((idx & 3) << 1) | ((idx >> 7) & 1);
            sh[k] = (idx >> 2) & 31;
        } else {
            // SROW=96 sources are linear layout
            wd[k] = idx >> 5;
            sh[k] = idx & 31;
        }
    }
    const uint32_t* mrow = memp + (long)n * MW;
    const int lane = tid & 63;
    const int nbase = blockIdx.x * 256 + (tid & ~63);  // wave's neuron base

#pragma unroll 4
    for (int bb = 0; bb < BCHUNK; ++bb) {
        const uint32_t* row = lds + bb * SRCW;
        uint32_t addr = 0;
#pragma unroll
        for (int k = 0; k < KBITS; k++)
            addr = (addr << 1) | ((row[wd[k]] >> sh[k]) & 1u);
        // mem tables are ballot layout: remap bit address -> (word, shift)
        uint32_t mw = ((addr >> 5) & ~7u) | ((addr & 3u) << 1) | ((addr >> 7) & 1u);
        uint32_t bit = (mrow[mw] >> ((addr >> 2) & 31u)) & 1u;
        const int b = b0 + bb;
        if (MODE == 2) {
            fout[(long)b * N_OUT + n] = (float)bit;
        } else {
            unsigned long long m = __ballot(bit != 0);
            if (lane == 0) {
                if (MODE == 0) {
                    *(unsigned long long*)(dst0 + (long)b * SROW + (nbase >> 5)) = m;
                    *(unsigned long long*)(dst1 + (long)b * SROW + (nbase >> 5)) = m;
                } else {
                    *(unsigned long long*)(dst0 + (long)b * SROW + 64 + (nbase >> 5)) = m;
                }
            }
        }
    }
}

// ---------------------------------------------------------------------------
extern "C" void kernel_launch(void* const* d_in, const int* in_sizes, int n_in,
                              void* d_out, int out_size, void* d_ws, size_t ws_size,
                              hipStream_t stream) {
    const int*   input_bits = (const int*)d_in[0];
    const int*   state_bits = (const int*)d_in[1];
    const int*   in_conn    = (const int*)d_in[2];
    const float* in_mem     = (const float*)d_in[3];
    const int*   st_conn    = (const int*)d_in[4];
    const float* st_mem     = (const float*)d_in[5];
    const int*   out_conn   = (const int*)d_in[6];
    const float* out_mem    = (const float*)d_in[7];
    float*       out        = (float*)d_out;

    // Workspace layout (all 256B-aligned):
    //   bits1 : [B][128] u32  = 1 MB   (packed input_bits, ballot layout)
    //   buf_s : [B][96]  u32  = 768 KB (s_inp bits: h_in | state, linear)
    //   buf_o : [B][96]  u32  = 768 KB (o_inp bits: h_in | s_out, linear)
    //   im_p  : [2048][512]   = 4 MB   (ballot layout)
    //   sm_p  : [1024][512]   = 2 MB   (ballot layout)
    //   om_p  : [1024][512]   = 2 MB   (ballot layout)
    char* ws = (char*)d_ws;
    uint32_t* bits1 = (uint32_t*)(ws);
    uint32_t* buf_s = (uint32_t*)(ws + 1048576);
    uint32_t* buf_o = (uint32_t*)(ws + 1048576 + 786432);
    uint32_t* im_p  = (uint32_t*)(ws + 1048576 + 2 * 786432);
    uint32_t* sm_p  = (uint32_t*)(ws + 1048576 + 2 * 786432 + 4194304);
    uint32_t* om_p  = (uint32_t*)(ws + 1048576 + 2 * 786432 + 4194304 + 2097152);

    // Bit-pack inputs (ballot layout; grid-strided for MLP).
    pack_input<<<2048, 256, 0, stream>>>(input_bits, bits1);
    pack_state<<<(BATCH * N_ST / 4) / 256, 256, 0, stream>>>((const int4*)state_bits, buf_s);
    pack_mem_all<<<2048, 256, 0, stream>>>(in_mem, st_mem, out_mem, im_p, sm_p, om_p);

    // Layer 1: input_bits -> h_in (written into both buf_s and buf_o, words 0..63)
    ram_layer<128, 16, 0><<<dim3(N_IN / 256, BATCH / 16), 256, 0, stream>>>(
        bits1, in_conn, im_p, buf_s, buf_o, nullptr);
    // Layer 2: s_inp -> s_out (into buf_o words 64..95)
    ram_layer<SROW, 8, 1><<<dim3(N_ST / 256, BATCH / 8), 256, 0, stream>>>(
        buf_s, st_conn, sm_p, buf_o, nullptr, nullptr);
    // Layer 3: o_inp -> output floats
    ram_layer<SROW, 8, 2><<<dim3(N_OUT / 256, BATCH / 8), 256, 0, stream>>>(
        buf_o, out_conn, om_p, nullptr, nullptr, out);
}